// Round 2
// baseline (537.692 us; speedup 1.0000x reference)
//
#include <hip/hip_runtime.h>
#include <hip/hip_bf16.h>
#include <stdint.h>

typedef __hip_bfloat16 bf16;
typedef __attribute__((ext_vector_type(8))) short bf16x8;   // 8 bf16 = 4 VGPRs
typedef __attribute__((ext_vector_type(4))) float f32x4;

#define MFMA16 __builtin_amdgcn_mfma_f32_16x16x32_bf16

__device__ __forceinline__ short f2b(float x) {
    bf16 h = __float2bfloat16(x);
    return *reinterpret_cast<short*>(&h);
}
__device__ __forceinline__ bf16x8 cvt8(const float4 a, const float4 b) {
    bf16x8 r;
    r[0] = f2b(a.x); r[1] = f2b(a.y); r[2] = f2b(a.z); r[3] = f2b(a.w);
    r[4] = f2b(b.x); r[5] = f2b(b.y); r[6] = f2b(b.z); r[7] = f2b(b.w);
    return r;
}

// ---------------------------------------------------------------------------
// C = A (MxK row-major) · B^T (B is NxK row-major, fp32)  ==  y = x @ W^T
// A is fp32 (A_F32) or bf16.  128x128 tile, BK=64, 256 thr / 4 waves.
// LDS stride 88 elems (176 B): 16B-aligned b128, max 2-way banks (free, m136).
// mode 0: row-major [M,N]; mode 1: scatter [B,H,S,D]; mode 2: scatter [B,H,D,S]
// ---------------------------------------------------------------------------
template<bool A_F32, bool OUT_F32>
__global__ __launch_bounds__(256, 2)
void gemm_bt(const void* __restrict__ Av, const float* __restrict__ B,
             void* __restrict__ Cv, int M, int N, int K, int mode)
{
    __shared__ bf16 As[128 * 88];
    __shared__ bf16 Bs[128 * 88];
    const int t    = threadIdx.x;
    const int wave = t >> 6;
    const int lane = t & 63;
    const int lr   = lane & 15;
    const int lq   = lane >> 4;
    const int m0   = blockIdx.x * 128;
    const int n0   = blockIdx.y * 128;
    const int wm   = (wave >> 1) * 64;
    const int wn   = (wave & 1) * 64;
    const int s_row = t >> 3;
    const int s_col = (t & 7) * 8;

    const float* Af = (const float*)Av;
    const bf16*  Ab = (const bf16*)Av;

    f32x4 acc[4][4];
#pragma unroll
    for (int i = 0; i < 4; ++i)
#pragma unroll
        for (int j = 0; j < 4; ++j) acc[i][j] = (f32x4)0.0f;

    for (int k0 = 0; k0 < K; k0 += 64) {
        __syncthreads();
#pragma unroll
        for (int i = 0; i < 4; ++i) {
            const int ar = m0 + s_row + i * 32;
            const int br = n0 + s_row + i * 32;
            bf16x8 va, vb;
            if (A_F32) {
                const float* ap = Af + (size_t)ar * K + k0 + s_col;
                va = cvt8(*(const float4*)ap, *(const float4*)(ap + 4));
            } else {
                va = *(const bf16x8*)(Ab + (size_t)ar * K + k0 + s_col);
            }
            const float* bp = B + (size_t)br * K + k0 + s_col;
            vb = cvt8(*(const float4*)bp, *(const float4*)(bp + 4));
            *(bf16x8*)(&As[(s_row + i * 32) * 88 + s_col]) = va;
            *(bf16x8*)(&Bs[(s_row + i * 32) * 88 + s_col]) = vb;
        }
        __syncthreads();
#pragma unroll
        for (int kk = 0; kk < 64; kk += 32) {
            bf16x8 af[4], bfr[4];
#pragma unroll
            for (int i = 0; i < 4; ++i)
                af[i] = *(const bf16x8*)(&As[(wm + i * 16 + lr) * 88 + kk + lq * 8]);
#pragma unroll
            for (int j = 0; j < 4; ++j)
                bfr[j] = *(const bf16x8*)(&Bs[(wn + j * 16 + lr) * 88 + kk + lq * 8]);
#pragma unroll
            for (int i = 0; i < 4; ++i)
#pragma unroll
                for (int j = 0; j < 4; ++j)
                    acc[i][j] = MFMA16(af[i], bfr[j], acc[i][j], 0, 0, 0);
        }
    }

    // C/D layout: col = lane&15, row = quad*4 + r   [m89-verified]
#pragma unroll
    for (int i = 0; i < 4; ++i) {
        const int mb = m0 + wm + i * 16 + lq * 4;
#pragma unroll
        for (int j = 0; j < 4; ++j) {
            const int n = n0 + wn + j * 16 + lr;
            if (mode == 2) {
                // V^T scatter [B,H,D,S]: 4 consecutive s (r=0..3), one 8B store
                const int b_ = mb >> 11, s_ = mb & 2047;
                const int h_ = n >> 7,  d_ = n & 127;
                bf16 pk[4];
#pragma unroll
                for (int r = 0; r < 4; ++r) pk[r] = __float2bfloat16(acc[i][j][r]);
                *(uint2*)((bf16*)Cv + (((b_ << 4) + h_) * 128 + d_) * 2048 + s_) =
                    *(const uint2*)pk;
            } else {
#pragma unroll
                for (int r = 0; r < 4; ++r) {
                    const int m = mb + r;
                    if (mode == 0) {
                        if (OUT_F32)
                            ((float*)Cv)[(size_t)m * N + n] = acc[i][j][r];
                        else
                            ((bf16*)Cv)[(size_t)m * N + n] = __float2bfloat16(acc[i][j][r]);
                    } else {            // mode 1: [B,H,S,D]
                        const int b_ = m >> 11, s_ = m & 2047;
                        const int h_ = n >> 7,  d_ = n & 127;
                        ((bf16*)Cv)[(((b_ << 4) + h_) * 2048 + s_) * 128 + d_] =
                            __float2bfloat16(acc[i][j][r]);
                    }
                }
            }
        }
    }
}

// ---------------------------------------------------------------------------
// Causal flash attention.  Q,K: [B,H,S,D] bf16; V: [B,H,D,S] bf16.
// Block 512 thr (8 waves x 16 q-rows = 128 q-tile), kv-tile 64.
// LDS: Ks 64x136 + Vs 128x88 + Ps 128x88 = 61 KB.
// ---------------------------------------------------------------------------
__global__ __launch_bounds__(512, 2)
void attn_fwd(const bf16* __restrict__ Q, const bf16* __restrict__ K,
              const bf16* __restrict__ V, bf16* __restrict__ O)
{
    __shared__ bf16 Ks[64 * 136];
    __shared__ bf16 Vs[128 * 88];
    __shared__ bf16 Ps[128 * 88];

    const int t    = threadIdx.x;
    const int wave = t >> 6;
    const int lane = t & 63;
    const int lr   = lane & 15;
    const int lq   = lane >> 4;

    const int bid  = blockIdx.x;
    const int half = bid >> 8;
    const int idx  = bid & 255;
    const int bh   = idx & 31;                  // b*16 + h
    const int qtl  = idx >> 5;
    const int qt   = half ? (15 - qtl) : qtl;   // pair-sum balance: 17 tiles

    const int bhS = bh * 2048;
    const int q0  = qt * 128;

    bf16x8 aq[4];
    {
        const bf16* qp = Q + (size_t)(bhS + q0 + wave * 16 + lr) * 128 + lq * 8;
#pragma unroll
        for (int ks = 0; ks < 4; ++ks) aq[ks] = *(const bf16x8*)(qp + ks * 32);
    }

    f32x4 acc_o[8];
#pragma unroll
    for (int j = 0; j < 8; ++j) acc_o[j] = (f32x4)0.0f;
    float mrow[4], lrow[4];
#pragma unroll
    for (int r = 0; r < 4; ++r) { mrow[r] = -INFINITY; lrow[r] = 0.0f; }

    const int krow = t >> 4;
    const int kcol = (t & 15) * 8;
    const int vrow = t >> 3;
    const int vcol = (t & 7) * 8;

    const float scale = 0.08838834764831845f;   // 1/sqrt(128)
    const float L2E   = 1.4426950408889634f;

    const int nkv = 2 * (qt + 1);
    for (int tile = 0; tile < nkv; ++tile) {
        const int kv0 = tile * 64;
#pragma unroll
        for (int i = 0; i < 2; ++i) {
            const int row = krow + i * 32;
            uint4 v = *(const uint4*)(K + (size_t)(bhS + kv0 + row) * 128 + kcol);
            *(uint4*)(&Ks[row * 136 + kcol]) = v;
        }
#pragma unroll
        for (int i = 0; i < 2; ++i) {
            const int row = vrow + i * 64;          // d
            uint4 v = *(const uint4*)(V + (size_t)(bh * 128 + row) * 2048 + kv0 + vcol);
            *(uint4*)(&Vs[row * 88 + vcol]) = v;
        }
        __syncthreads();

        f32x4 acc_s[4];
#pragma unroll
        for (int j = 0; j < 4; ++j) acc_s[j] = (f32x4)0.0f;
#pragma unroll
        for (int ks = 0; ks < 4; ++ks) {
#pragma unroll
            for (int j = 0; j < 4; ++j) {
                bf16x8 bk = *(const bf16x8*)(&Ks[(j * 16 + lr) * 136 + ks * 32 + lq * 8]);
                acc_s[j] = MFMA16(aq[ks], bk, acc_s[j], 0, 0, 0);
            }
        }

        const int qrow_g = q0 + wave * 16 + lq * 4;
        float mnew[4], alpha[4];
#pragma unroll
        for (int r = 0; r < 4; ++r) {
            float mx = -1e30f;
#pragma unroll
            for (int j = 0; j < 4; ++j) {
                float s = acc_s[j][r] * scale;
                const int kvg = kv0 + j * 16 + lr;
                s = (kvg > qrow_g + r) ? -1e30f : s;
                acc_s[j][r] = s;
                mx = fmaxf(mx, s);
            }
#pragma unroll
            for (int o = 1; o < 16; o <<= 1) mx = fmaxf(mx, __shfl_xor(mx, o));
            mnew[r]  = fmaxf(mrow[r], mx);
            alpha[r] = exp2f((mrow[r] - mnew[r]) * L2E);
            mrow[r]  = mnew[r];
        }
#pragma unroll
        for (int r = 0; r < 4; ++r) {
            float rs = 0.0f;
#pragma unroll
            for (int j = 0; j < 4; ++j) {
                float p = exp2f((acc_s[j][r] - mnew[r]) * L2E);
                rs += p;
                Ps[(wave * 16 + lq * 4 + r) * 88 + j * 16 + lr] = __float2bfloat16(p);
            }
#pragma unroll
            for (int o = 1; o < 16; o <<= 1) rs += __shfl_xor(rs, o);
            lrow[r] = lrow[r] * alpha[r] + rs;
#pragma unroll
            for (int j = 0; j < 8; ++j) acc_o[j][r] *= alpha[r];
        }

#pragma unroll
        for (int ks = 0; ks < 2; ++ks) {
            bf16x8 ap = *(const bf16x8*)(&Ps[(wave * 16 + lr) * 88 + ks * 32 + lq * 8]);
#pragma unroll
            for (int j = 0; j < 8; ++j) {
                bf16x8 bv = *(const bf16x8*)(&Vs[(j * 16 + lr) * 88 + ks * 32 + lq * 8]);
                acc_o[j] = MFMA16(ap, bv, acc_o[j], 0, 0, 0);
            }
        }
        __syncthreads();
    }

    const int b_ = bh >> 4, h_ = bh & 15;
#pragma unroll
    for (int r = 0; r < 4; ++r) {
        const float inv = 1.0f / lrow[r];
        const int row = q0 + wave * 16 + lq * 4 + r;
#pragma unroll
        for (int j = 0; j < 8; ++j) {
            const int col = h_ * 128 + j * 16 + lr;
            O[(size_t)(b_ * 2048 + row) * 2048 + col] =
                __float2bfloat16(acc_o[j][r] * inv);
        }
    }
}

extern "C" void kernel_launch(void* const* d_in, const int* in_sizes, int n_in,
                              void* d_out, int out_size, void* d_ws, size_t ws_size,
                              hipStream_t stream)
{
    const float* x  = (const float*)d_in[0];
    const float* Wq = (const float*)d_in[1];
    const float* Wk = (const float*)d_in[2];
    const float* Wv = (const float*)d_in[3];
    const float* Wo = (const float*)d_in[4];
    float* out = (float*)d_out;

    const size_t NE = 8388608;          // B*S*E
    bf16* Qb = (bf16*)d_ws;             // [B,H,S,D]
    bf16* Kb = Qb + NE;                 // [B,H,S,D]
    bf16* Vb = Kb + NE;                 // [B,H,D,S]
    bf16* AO = Vb + NE;                 // [B,S,E] bf16

    dim3 gg(32, 16), gb(256);
    gemm_bt<true,  false><<<gg, gb, 0, stream>>>(x,  Wq, Qb,  4096, 2048, 2048, 1);
    gemm_bt<true,  false><<<gg, gb, 0, stream>>>(x,  Wk, Kb,  4096, 2048, 2048, 1);
    gemm_bt<true,  false><<<gg, gb, 0, stream>>>(x,  Wv, Vb,  4096, 2048, 2048, 2);
    attn_fwd<<<dim3(512), dim3(512), 0, stream>>>(Qb, Kb, Vb, AO);
    gemm_bt<false, true ><<<gg, gb, 0, stream>>>(AO, Wo, out, 4096, 2048, 2048, 0);
}

// Round 3
// 480.311 us; speedup vs baseline: 1.1195x; 1.1195x over previous
//
#include <hip/hip_runtime.h>
#include <hip/hip_bf16.h>
#include <stdint.h>

typedef __hip_bfloat16 bf16;
typedef __attribute__((ext_vector_type(8))) short bf16x8;   // 8 bf16 = 4 VGPRs
typedef __attribute__((ext_vector_type(4))) float f32x4;

#define MFMA16 __builtin_amdgcn_mfma_f32_16x16x32_bf16

// async global->LDS, 16B per lane; LDS dest = wave-uniform base + lane*16
__device__ __forceinline__ void gll16(const bf16* g, const bf16* l) {
    __builtin_amdgcn_global_load_lds(
        (const __attribute__((address_space(1))) void*)g,
        (__attribute__((address_space(3))) void*)(bf16*)l, 16, 0, 0);
}

__device__ __forceinline__ short f2b(float x) {
    bf16 h = __float2bfloat16(x);
    return *reinterpret_cast<short*>(&h);
}

// ---------------------------------------------------------------------------
// fp32 -> bf16 bulk convert (memory-bound), 8 elems/thread
// ---------------------------------------------------------------------------
__global__ void cvt_f32_bf16(const float* __restrict__ src, bf16* __restrict__ dst,
                             int n) {
    int i = (blockIdx.x * blockDim.x + threadIdx.x) * 8;
    if (i >= n) return;
    float4 a = *(const float4*)(src + i);
    float4 b = *(const float4*)(src + i + 4);
    bf16x8 v;
    v[0] = f2b(a.x); v[1] = f2b(a.y); v[2] = f2b(a.z); v[3] = f2b(a.w);
    v[4] = f2b(b.x); v[5] = f2b(b.y); v[6] = f2b(b.z); v[7] = f2b(b.w);
    *(bf16x8*)(dst + i) = v;
}

// ---------------------------------------------------------------------------
// C = A (MxK bf16 rm) . B^T (B NxK bf16 rm)  ==  y = x @ W^T
// m97 structure: 128x128 tile, BK=64, unpadded LDS [128][64], global_load_lds
// width 16, 2-barrier K-loop.  256 thr / 4 waves, 4x4 MFMA 16x16x32 each.
// mode 0: fp32 row-major [M,N]; mode 1: bf16 [B,H,S,D]; mode 2: bf16 [B,H,D,S]
// ---------------------------------------------------------------------------
__global__ __launch_bounds__(256, 2)
void gemm_bt(const bf16* __restrict__ A, const bf16* __restrict__ B,
             void* __restrict__ Cv, int M, int N, int K, int mode)
{
    __shared__ bf16 As[128 * 64];
    __shared__ bf16 Bs[128 * 64];
    const int t    = threadIdx.x;
    const int wave = t >> 6;
    const int lane = t & 63;
    const int lr   = lane & 15;
    const int lq   = lane >> 4;
    const int m0   = blockIdx.x * 128;
    const int n0   = blockIdx.y * 128;
    const int wm   = (wave >> 1) * 64;
    const int wn   = (wave & 1) * 64;

    f32x4 acc[4][4];
#pragma unroll
    for (int i = 0; i < 4; ++i)
#pragma unroll
        for (int j = 0; j < 4; ++j) acc[i][j] = (f32x4)0.0f;

    // staging: wave w covers rows [w*32, w*32+32); per call 8 rows
    const int arow0 = wave * 32;
    const int g_row = lane >> 3;          // 0..7
    const int g_col = (lane & 7) * 8;     // elem col
    const bf16* Agw = A + (size_t)(m0 + arow0 + g_row) * K + g_col;
    const bf16* Bgw = B + (size_t)(n0 + arow0 + g_row) * K + g_col;
    const bf16* AsW = As + arow0 * 64;
    const bf16* BsW = Bs + arow0 * 64;

    for (int k0 = 0; k0 < K; k0 += 64) {
        __syncthreads();
#pragma unroll
        for (int c = 0; c < 4; ++c)
            gll16(Agw + (size_t)(c * 8) * K + k0, AsW + c * 8 * 64);
#pragma unroll
        for (int c = 0; c < 4; ++c)
            gll16(Bgw + (size_t)(c * 8) * K + k0, BsW + c * 8 * 64);
        __syncthreads();
#pragma unroll
        for (int kk = 0; kk < 64; kk += 32) {
            bf16x8 af[4], bfr[4];
#pragma unroll
            for (int i = 0; i < 4; ++i)
                af[i] = *(const bf16x8*)(&As[(wm + i * 16 + lr) * 64 + kk + lq * 8]);
#pragma unroll
            for (int j = 0; j < 4; ++j)
                bfr[j] = *(const bf16x8*)(&Bs[(wn + j * 16 + lr) * 64 + kk + lq * 8]);
#pragma unroll
            for (int i = 0; i < 4; ++i)
#pragma unroll
                for (int j = 0; j < 4; ++j)
                    acc[i][j] = MFMA16(af[i], bfr[j], acc[i][j], 0, 0, 0);
        }
    }

    // C/D layout: col = lane&15, row = quad*4 + r   [m89-verified]
#pragma unroll
    for (int i = 0; i < 4; ++i) {
        const int mb = m0 + wm + i * 16 + lq * 4;
#pragma unroll
        for (int j = 0; j < 4; ++j) {
            const int n = n0 + wn + j * 16 + lr;
            if (mode == 2) {
                // [B,H,D,S]: 4 consecutive s (r=0..3), one 8B store
                const int b_ = mb >> 11, s_ = mb & 2047;
                const int h_ = n >> 7,  d_ = n & 127;
                bf16 pk[4];
#pragma unroll
                for (int r = 0; r < 4; ++r) pk[r] = __float2bfloat16(acc[i][j][r]);
                *(uint2*)((bf16*)Cv + (size_t)(((b_ << 4) + h_) * 128 + d_) * 2048 + s_) =
                    *(const uint2*)pk;
            } else if (mode == 1) {
#pragma unroll
                for (int r = 0; r < 4; ++r) {
                    const int m = mb + r;
                    const int b_ = m >> 11, s_ = m & 2047;
                    const int h_ = n >> 7,  d_ = n & 127;
                    ((bf16*)Cv)[(size_t)(((b_ << 4) + h_) * 2048 + s_) * 128 + d_] =
                        __float2bfloat16(acc[i][j][r]);
                }
            } else {
#pragma unroll
                for (int r = 0; r < 4; ++r)
                    ((float*)Cv)[(size_t)(mb + r) * N + n] = acc[i][j][r];
            }
        }
    }
}

// ---------------------------------------------------------------------------
// Causal flash attention, S^T formulation.
// Q,K: [B,H,S,D] bf16; V: [B,H,D,S] bf16; O (=AO): [B,S,E] bf16.
// Block 512 thr / 8 waves; q-tile 128 (16 q per wave, one q per lane);
// kv-tile 64.  S^T = K.Q^T (A=K, B=Q) -> lane owns col q: mask/max/sum are
// lane-local + 2 shfls.  PV: O^T = V^T . P^T with P^T stored [q][kv] (vector
// 8B writes, b128 reads).  O^T transposed via LDS for coalesced stores.
// LDS: Ks 64x128 (16K) + Vs 128x64 (16K) + Pb 128x72 (18K) = 50K; 2 blk/CU.
// ---------------------------------------------------------------------------
__global__ __launch_bounds__(512, 2)
void attn_fwd(const bf16* __restrict__ Q, const bf16* __restrict__ K,
              const bf16* __restrict__ V, bf16* __restrict__ O)
{
    __shared__ bf16 smem[25600];          // 51.2 KB
    bf16* Ks = smem;                      // [64][128]
    bf16* Vs = smem + 8192;               // [128][64]
    bf16* Pb = smem + 16384;              // [128][72]
    bf16* Ot = smem;                      // reuse: per wave [16][136]

    const int t    = threadIdx.x;
    const int wave = t >> 6;
    const int lane = t & 63;
    const int lr   = lane & 15;
    const int lq   = lane >> 4;

    const int bid  = blockIdx.x;
    const int half = bid >> 8;
    const int idx  = bid & 255;
    const int bh   = idx & 31;                  // b*16 + h
    const int qtl  = idx >> 5;
    const int qt   = half ? (15 - qtl) : qtl;   // pair-sum balance

    const int bhS = bh * 2048;
    const int q0  = qt * 128;
    const int q_g = q0 + wave * 16 + lr;        // this lane's q row (global)

    // Q fragment, B-operand layout: lane holds q=lane&15, d=quad*8+j
    bf16x8 aq[4];
    {
        const bf16* qp = Q + (size_t)(bhS + q_g) * 128 + lq * 8;
#pragma unroll
        for (int ks = 0; ks < 4; ++ks) aq[ks] = *(const bf16x8*)(qp + ks * 32);
    }

    f32x4 acc_o[8];                       // O^T: row d = i*16+lq*4+r, col q=lr
#pragma unroll
    for (int i = 0; i < 8; ++i) acc_o[i] = (f32x4)0.0f;
    float mrow = -INFINITY, lrow = 0.0f;  // one q per lane

    const float scale = 0.08838834764831845f;   // 1/sqrt(128)
    const float L2E   = 1.4426950408889634f;

    const bf16* Kw = K + (size_t)(bhS + wave * 8 + (lane >> 4)) * 128 + (lane & 15) * 8;
    const bf16* Vw = V + (size_t)(bh * 128 + wave * 16 + (lane >> 3)) * 2048 + (lane & 7) * 8;
    const bf16* KsW = Ks + wave * 8 * 128;
    const bf16* VsW = Vs + wave * 16 * 64;
    bf16* PbW = Pb + (wave * 16 + lr) * 72;

    const int nkv = 2 * (qt + 1);
    for (int tile = 0; tile < nkv; ++tile) {
        const int kv0 = tile * 64;
        __syncthreads();
        // Ks: wave covers kv rows [wave*8, wave*8+8), 4 rows / call
        gll16(Kw + (size_t)kv0 * 128,             KsW);
        gll16(Kw + (size_t)(kv0 + 4) * 128,       KsW + 4 * 128);
        // Vs: wave covers d rows [wave*16, wave*16+16), 8 rows / call
        gll16(Vw + kv0,                           VsW);
        gll16(Vw + 8 * 2048 + kv0,                VsW + 8 * 64);
        __syncthreads();

        // ---- S^T = K . Q^T : acc_s[j] covers kv = j*16 + lq*4 + r ----
        f32x4 acc_s[4];
#pragma unroll
        for (int j = 0; j < 4; ++j) acc_s[j] = (f32x4)0.0f;
#pragma unroll
        for (int ks = 0; ks < 4; ++ks) {
#pragma unroll
            for (int j = 0; j < 4; ++j) {
                bf16x8 ak = *(const bf16x8*)(&Ks[(j * 16 + lr) * 128 + ks * 32 + lq * 8]);
                acc_s[j] = MFMA16(ak, aq[ks], acc_s[j], 0, 0, 0);
            }
        }

        // ---- softmax: lane owns column q = q_g ----
        float mx = -1e30f;
#pragma unroll
        for (int j = 0; j < 4; ++j)
#pragma unroll
            for (int r = 0; r < 4; ++r) {
                float s = acc_s[j][r] * scale;
                const int kvg = kv0 + j * 16 + lq * 4 + r;
                s = (kvg > q_g) ? -1e30f : s;
                acc_s[j][r] = s;
                mx = fmaxf(mx, s);
            }
        mx = fmaxf(mx, __shfl_xor(mx, 16));
        mx = fmaxf(mx, __shfl_xor(mx, 32));
        const float mnew  = fmaxf(mrow, mx);
        const float alpha = exp2f((mrow - mnew) * L2E);
        mrow = mnew;

        float rs = 0.0f;
#pragma unroll
        for (int j = 0; j < 4; ++j) {
            bf16 pk[4];
#pragma unroll
            for (int r = 0; r < 4; ++r) {
                float p = exp2f((acc_s[j][r] - mnew) * L2E);
                rs += p;
                pk[r] = __float2bfloat16(p);
            }
            *(uint2*)(PbW + j * 16 + lq * 4) = *(const uint2*)pk;   // P^T[q][kv]
        }
        rs += __shfl_xor(rs, 16);
        rs += __shfl_xor(rs, 32);
        lrow = lrow * alpha + rs;
#pragma unroll
        for (int i = 0; i < 8; ++i)
#pragma unroll
            for (int r = 0; r < 4; ++r) acc_o[i][r] *= alpha;

        // ---- O^T += V^T . P^T ----
#pragma unroll
        for (int ks = 0; ks < 2; ++ks) {
            bf16x8 bp = *(const bf16x8*)(PbW + ks * 32 + lq * 8);
#pragma unroll
            for (int i = 0; i < 8; ++i) {
                bf16x8 av = *(const bf16x8*)(&Vs[(i * 16 + lr) * 64 + ks * 32 + lq * 8]);
                acc_o[i] = MFMA16(av, bp, acc_o[i], 0, 0, 0);
            }
        }
    }

    // ---- epilogue: transpose O^T through LDS, coalesced global stores ----
    __syncthreads();                      // done with Ks/Vs/Pb
    const float inv = 1.0f / lrow;
    bf16* OtW = Ot + wave * 16 * 136;
#pragma unroll
    for (int i = 0; i < 8; ++i) {
        bf16 pk[4];
#pragma unroll
        for (int r = 0; r < 4; ++r) pk[r] = __float2bfloat16(acc_o[i][r] * inv);
        *(uint2*)(OtW + lr * 136 + i * 16 + lq * 4) = *(const uint2*)pk;
    }
    const int b_ = bh >> 4, h_ = bh & 15;
    const int ro = lane >> 2;             // 0..15 (q row within wave tile)
    const int dc = (lane & 3) * 32;       // d chunk
    const bf16* src = OtW + ro * 136 + dc;
    bf16* dst = O + (size_t)(b_ * 2048 + q0 + wave * 16 + ro) * 2048 + h_ * 128 + dc;
#pragma unroll
    for (int u = 0; u < 4; ++u)
        *(uint4*)(dst + u * 8) = *(const uint4*)(src + u * 8);
}

extern "C" void kernel_launch(void* const* d_in, const int* in_sizes, int n_in,
                              void* d_out, int out_size, void* d_ws, size_t ws_size,
                              hipStream_t stream)
{
    const float* x  = (const float*)d_in[0];
    const float* Wq = (const float*)d_in[1];
    const float* Wk = (const float*)d_in[2];
    const float* Wv = (const float*)d_in[3];
    const float* Wo = (const float*)d_in[4];
    float* out = (float*)d_out;

    const size_t NX = 8388608;            // B*S*E elems
    const size_t NW = 4194304;            // E*E elems
    bf16* Xb  = (bf16*)d_ws;              // [B*S, E]        (later reused as AO)
    bf16* W1  = Xb + NX;                  // Wq, later Wo
    bf16* W2  = W1 + NW;                  // Wk
    bf16* W3  = W2 + NW;                  // Wv
    bf16* Qb  = W3 + NW;                  // [B,H,S,D]
    bf16* Kb  = Qb + NX;                  // [B,H,S,D]
    bf16* Vb  = Kb + NX;                  // [B,H,D,S]
    bf16* AO  = Xb;                       // [B,S,E] (x dead after QKV gemms)

    cvt_f32_bf16<<<NX / (256 * 8), 256, 0, stream>>>(x,  Xb, (int)NX);
    cvt_f32_bf16<<<NW / (256 * 8), 256, 0, stream>>>(Wq, W1, (int)NW);
    cvt_f32_bf16<<<NW / (256 * 8), 256, 0, stream>>>(Wk, W2, (int)NW);
    cvt_f32_bf16<<<NW / (256 * 8), 256, 0, stream>>>(Wv, W3, (int)NW);

    dim3 gg(32, 16), gb(256);
    gemm_bt<<<gg, gb, 0, stream>>>(Xb, W1, Qb, 4096, 2048, 2048, 1);
    gemm_bt<<<gg, gb, 0, stream>>>(Xb, W2, Kb, 4096, 2048, 2048, 1);
    gemm_bt<<<gg, gb, 0, stream>>>(Xb, W3, Vb, 4096, 2048, 2048, 2);

    cvt_f32_bf16<<<NW / (256 * 8), 256, 0, stream>>>(Wo, W1, (int)NW);
    attn_fwd<<<dim3(512), dim3(512), 0, stream>>>(Qb, Kb, Vb, AO);
    gemm_bt<<<gg, gb, 0, stream>>>(AO, W1, out, 4096, 2048, 2048, 0);
}

// Round 5
// 343.509 us; speedup vs baseline: 1.5653x; 1.3982x over previous
//
#include <hip/hip_runtime.h>
#include <hip/hip_bf16.h>
#include <stdint.h>

typedef __hip_bfloat16 bf16;
typedef __attribute__((ext_vector_type(8))) short bf16x8;   // 8 bf16 = 4 VGPRs
typedef __attribute__((ext_vector_type(4))) float f32x4;

#define MFMA16 __builtin_amdgcn_mfma_f32_16x16x32_bf16

// async global->LDS, 16B/lane; LDS dest = wave-uniform base + lane*16
__device__ __forceinline__ void gll16(const bf16* g, const bf16* l) {
    __builtin_amdgcn_global_load_lds(
        (const __attribute__((address_space(1))) void*)g,
        (__attribute__((address_space(3))) void*)(bf16*)l, 16, 0, 0);
}

__device__ __forceinline__ short f2b(float x) {
    bf16 h = __float2bfloat16(x);
    return *reinterpret_cast<short*>(&h);
}
__device__ __forceinline__ float b2f(short s) {
    union { uint32_t u; float f; } cv;
    cv.u = ((uint32_t)(uint16_t)s) << 16;
    return cv.f;
}

// ---------------------------------------------------------------------------
// fp32 -> bf16: one kernel for x + Wq + Wk + Wv (block-range dispatch)
// ---------------------------------------------------------------------------
__global__ void cvt4(const float* __restrict__ x,  const float* __restrict__ wq,
                     const float* __restrict__ wk, const float* __restrict__ wv,
                     bf16* __restrict__ xb, bf16* __restrict__ w1,
                     bf16* __restrict__ w2, bf16* __restrict__ w3)
{
    int b = blockIdx.x;
    const float* s; bf16* d; int base;
    if      (b < 4096) { s = x;  d = xb; base = b; }
    else if (b < 6144) { s = wq; d = w1; base = b - 4096; }
    else if (b < 8192) { s = wk; d = w2; base = b - 6144; }
    else               { s = wv; d = w3; base = b - 8192; }
    int i = base * 2048 + threadIdx.x * 8;
    float4 a = *(const float4*)(s + i);
    float4 c = *(const float4*)(s + i + 4);
    bf16x8 v;
    v[0] = f2b(a.x); v[1] = f2b(a.y); v[2] = f2b(a.z); v[3] = f2b(a.w);
    v[4] = f2b(c.x); v[5] = f2b(c.y); v[6] = f2b(c.z); v[7] = f2b(c.w);
    *(bf16x8*)(d + i) = v;
}
__global__ void cvt1(const float* __restrict__ s, bf16* __restrict__ d) {
    int i = blockIdx.x * 2048 + threadIdx.x * 8;
    float4 a = *(const float4*)(s + i);
    float4 c = *(const float4*)(s + i + 4);
    bf16x8 v;
    v[0] = f2b(a.x); v[1] = f2b(a.y); v[2] = f2b(a.z); v[3] = f2b(a.w);
    v[4] = f2b(c.x); v[5] = f2b(c.y); v[6] = f2b(c.z); v[7] = f2b(c.w);
    *(bf16x8*)(d + i) = v;
}

// ---------------------------------------------------------------------------
// GEMM core: acc[4][4] += A-tile(128 rows @ m0) . B-tile(128 rows @ n0)^T.
// XOR-swizzled unpadded LDS [128][64]: chunk (r,c) stored at (r, c^(r&7)).
// gll16 staging fetches the permuted global chunk so reads are conflict-free.
// ---------------------------------------------------------------------------
__device__ __forceinline__ void gemm_core(const bf16* __restrict__ A,
                                          const bf16* __restrict__ Bw, int K,
                                          int m0, int n0,
                                          bf16* As, bf16* Bs, f32x4 acc[4][4])
{
    const int t    = threadIdx.x;
    const int wave = t >> 6;
    const int lane = t & 63;
    const int lr   = lane & 15;
    const int lq   = lane >> 4;
    const int wm   = (wave >> 1) * 64;
    const int wn   = (wave & 1) * 64;
    const int r8   = lane >> 3;            // staging row-in-8
    const int c8   = lane & 7;             // staging chunk
    const int gly  = ((c8 ^ r8) << 3);     // swizzled global col (elems)

    const bf16* Ag = A  + (size_t)(m0 + wave * 32 + r8) * K + gly;
    const bf16* Bg = Bw + (size_t)(n0 + wave * 32 + r8) * K + gly;
    bf16* AsW = As + wave * 32 * 64;
    bf16* BsW = Bs + wave * 32 * 64;
    const int sw0 = ((lq ^ (lr & 7)) << 3);         // kk=0  read swizzle
    const int sw1 = (((4 + lq) ^ (lr & 7)) << 3);   // kk=32

    for (int k0 = 0; k0 < K; k0 += 64) {
        __syncthreads();
#pragma unroll
        for (int c = 0; c < 4; ++c) {
            gll16(Ag + (size_t)(c * 8) * K + k0, AsW + c * 512);
            gll16(Bg + (size_t)(c * 8) * K + k0, BsW + c * 512);
        }
        __syncthreads();
#pragma unroll
        for (int kk = 0; kk < 2; ++kk) {
            const int sw = kk ? sw1 : sw0;
            bf16x8 af[4], bfr[4];
#pragma unroll
            for (int i = 0; i < 4; ++i)
                af[i] = *(const bf16x8*)(&As[(wm + i * 16 + lr) * 64 + sw]);
#pragma unroll
            for (int j = 0; j < 4; ++j)
                bfr[j] = *(const bf16x8*)(&Bs[(wn + j * 16 + lr) * 64 + sw]);
#pragma unroll
            for (int i = 0; i < 4; ++i)
#pragma unroll
                for (int j = 0; j < 4; ++j)
                    acc[i][j] = MFMA16(af[i], bfr[j], acc[i][j], 0, 0, 0);
        }
    }
}

// ---------------------------------------------------------------------------
// Fused QKV projection: grid (32, 48); blockIdx.y>>4 selects Wq/Wk/Wv.
// Q,K -> [B,H,S,D]; V -> [B,H,D,S].
// ---------------------------------------------------------------------------
__global__ __launch_bounds__(256, 2)
void gemm_qkv(const bf16* __restrict__ A,
              const bf16* __restrict__ Wq, const bf16* __restrict__ Wk,
              const bf16* __restrict__ Wv,
              bf16* __restrict__ Qo, bf16* __restrict__ Ko, bf16* __restrict__ Vo)
{
    __shared__ bf16 As[128 * 64];
    __shared__ bf16 Bs[128 * 64];
    const int sel = blockIdx.y >> 4;
    const int n0  = (blockIdx.y & 15) * 128;
    const int m0  = blockIdx.x * 128;
    const bf16* Bw = sel == 0 ? Wq : sel == 1 ? Wk : Wv;
    bf16* Cv = sel == 0 ? Qo : sel == 1 ? Ko : Vo;

    f32x4 acc[4][4];
#pragma unroll
    for (int i = 0; i < 4; ++i)
#pragma unroll
        for (int j = 0; j < 4; ++j) acc[i][j] = (f32x4)0.0f;

    gemm_core(A, Bw, 2048, m0, n0, As, Bs, acc);

    const int t = threadIdx.x, wave = t >> 6, lane = t & 63;
    const int lr = lane & 15, lq = lane >> 4;
    const int wm = (wave >> 1) * 64, wn = (wave & 1) * 64;
#pragma unroll
    for (int i = 0; i < 4; ++i) {
        const int mb = m0 + wm + i * 16 + lq * 4;
#pragma unroll
        for (int j = 0; j < 4; ++j) {
            const int n = n0 + wn + j * 16 + lr;
            const int h_ = n >> 7, d_ = n & 127;
            if (sel == 2) {
                // [B,H,D,S]: r=0..3 are consecutive s -> one 8B store
                const int b_ = mb >> 11, s_ = mb & 2047;
                bf16 pk[4];
#pragma unroll
                for (int r = 0; r < 4; ++r) pk[r] = __float2bfloat16(acc[i][j][r]);
                *(uint2*)(Cv + (size_t)(((b_ << 4) + h_) * 128 + d_) * 2048 + s_) =
                    *(const uint2*)pk;
            } else {
#pragma unroll
                for (int r = 0; r < 4; ++r) {
                    const int m = mb + r;
                    const int b_ = m >> 11, s_ = m & 2047;
                    Cv[(size_t)(((b_ << 4) + h_) * 2048 + s_) * 128 + d_] =
                        __float2bfloat16(acc[i][j][r]);
                }
            }
        }
    }
}

// ---------------------------------------------------------------------------
// Output projection: C(fp32)[M,N] = A(bf16) . Wo(bf16)^T
// ---------------------------------------------------------------------------
__global__ __launch_bounds__(256, 2)
void gemm_o(const bf16* __restrict__ A, const bf16* __restrict__ Bw,
            float* __restrict__ C, int N)
{
    __shared__ bf16 As[128 * 64];
    __shared__ bf16 Bs[128 * 64];
    const int m0 = blockIdx.x * 128;
    const int n0 = blockIdx.y * 128;

    f32x4 acc[4][4];
#pragma unroll
    for (int i = 0; i < 4; ++i)
#pragma unroll
        for (int j = 0; j < 4; ++j) acc[i][j] = (f32x4)0.0f;

    gemm_core(A, Bw, 2048, m0, n0, As, Bs, acc);

    const int t = threadIdx.x, wave = t >> 6, lane = t & 63;
    const int lr = lane & 15, lq = lane >> 4;
    const int wm = (wave >> 1) * 64, wn = (wave & 1) * 64;
#pragma unroll
    for (int i = 0; i < 4; ++i) {
        const int mb = m0 + wm + i * 16 + lq * 4;
#pragma unroll
        for (int j = 0; j < 4; ++j) {
            const int n = n0 + wn + j * 16 + lr;
#pragma unroll
            for (int r = 0; r < 4; ++r)
                C[(size_t)(mb + r) * N + n] = acc[i][j][r];
        }
    }
}

// ---------------------------------------------------------------------------
// Causal flash attention, S^T form, XOR-swizzled LDS, K/V double-buffered.
// Q,K: [B,H,S,D]; V: [B,H,D,S]; O: [B,S,E] bf16.
// Block 512 thr / 8 waves; q-tile 128 (one q per lane), kv-tile 64.
// LDS: 2*Ks(16K) + 2*Vs(16K) + Pb(16K) = 80 KB -> exactly 2 blocks/CU.
// One barrier per tile; next tile's gll16 issued before compute.
// ---------------------------------------------------------------------------
__global__ __launch_bounds__(512, 4)
void attn_fwd(const bf16* __restrict__ Q, const bf16* __restrict__ K,
              const bf16* __restrict__ V, bf16* __restrict__ O)
{
    __shared__ bf16 smem[40960];              // 80 KB
    bf16* KsB0 = smem;                        // [64][128] swizzled
    bf16* KsB1 = smem + 8192;
    bf16* VsB0 = smem + 16384;                // [128][64] swizzled
    bf16* VsB1 = smem + 24576;
    bf16* Pb   = smem + 32768;                // per-wave [16][64] swizzled

    const int t    = threadIdx.x;
    const int wave = t >> 6;
    const int lane = t & 63;
    const int lr   = lane & 15;
    const int lq   = lane >> 4;

    const int bid  = blockIdx.x;
    const int half = bid >> 8;
    const int idx  = bid & 255;
    const int bh   = idx & 31;                // b*16 + h
    const int qtl  = idx >> 5;
    const int qt   = half ? (15 - qtl) : qtl;

    const int bhS = bh * 2048;
    const int q0  = qt * 128;
    const int q_g = q0 + wave * 16 + lr;      // lane's q row

    const float scale = 0.08838834764831845f; // 1/sqrt(128)
    const float L2E   = 1.4426950408889634f;
    const float SC    = scale * L2E;          // fold into Q fragment

    // Q fragment (B-operand), pre-scaled by scale*log2(e)
    bf16x8 aq[4];
    {
        const bf16* qp = Q + (size_t)(bhS + q_g) * 128 + lq * 8;
#pragma unroll
        for (int ks = 0; ks < 4; ++ks) {
            bf16x8 v = *(const bf16x8*)(qp + ks * 32);
#pragma unroll
            for (int e = 0; e < 8; ++e)
                v[e] = f2b(b2f(v[e]) * SC);
            aq[ks] = v;
        }
    }

    // staging sources (global addresses pre-swizzled to match LDS dest)
    const bf16* Kp0 = K + (size_t)(bhS + wave * 8 + (lane >> 4)) * 128
                        + (((lane & 15) ^ (lane >> 4)) << 3);
    const bf16* Kp1 = K + (size_t)(bhS + wave * 8 + 4 + (lane >> 4)) * 128
                        + (((lane & 15) ^ (4 + (lane >> 4))) << 3);
    const bf16* Vp0 = V + (size_t)(bh * 128 + wave * 16 + (lane >> 3)) * 2048
                        + (((lane & 7) ^ (lane >> 3)) << 3);

    // read-side swizzles (row&7 == lr&7 for all read rows)
    int swz[4];
#pragma unroll
    for (int ks = 0; ks < 4; ++ks) swz[ks] = (((ks * 4 + lq) ^ (lr & 7)) << 3);
    // Pb write offsets: chunk (j*2 + lq>>1) ^ (lr&7), half lq&1
    int pw[4];
#pragma unroll
    for (int j = 0; j < 4; ++j)
        pw[j] = ((((j * 2) + (lq >> 1)) ^ (lr & 7)) << 3) + ((lq & 1) << 2);
    bf16* PbRow = Pb + (wave * 16 + lr) * 64;

    f32x4 acc_o[8];
#pragma unroll
    for (int i = 0; i < 8; ++i) acc_o[i] = (f32x4)0.0f;
    float mrow = -INFINITY, lrow = 0.0f;

    const int nkv = 2 * (qt + 1);
    // stage tile 0 into buffer 0
    {
        gll16(Kp0, KsB0 + wave * 1024);
        gll16(Kp1, KsB0 + wave * 1024 + 512);
        gll16(Vp0, VsB0 + wave * 1024);
        gll16(Vp0 + 8 * 2048, VsB0 + wave * 1024 + 512);
    }

    for (int tile = 0; tile < nkv; ++tile) {
        __syncthreads();                       // tile's loads landed; prev reads done
        const int cur = tile & 1;
        const bf16* KsC = cur ? KsB1 : KsB0;
        const bf16* VsC = cur ? VsB1 : VsB0;
        if (tile + 1 < nkv) {                  // prefetch next into other buffer
            bf16* Kd = (cur ? KsB0 : KsB1) + wave * 1024;
            bf16* Vd = (cur ? VsB0 : VsB1) + wave * 1024;
            const size_t ko = (size_t)(tile + 1) * 64 * 128;
            const int    vo = (tile + 1) * 64;
            gll16(Kp0 + ko, Kd);
            gll16(Kp1 + ko, Kd + 512);
            gll16(Vp0 + vo, Vd);
            gll16(Vp0 + 8 * 2048 + vo, Vd + 512);
        }

        // ---- S'^T = (K.Q^T)*SC : acc_s[j] covers kv = j*16 + lq*4 + r ----
        f32x4 acc_s[4];
#pragma unroll
        for (int j = 0; j < 4; ++j) acc_s[j] = (f32x4)0.0f;
#pragma unroll
        for (int ks = 0; ks < 4; ++ks) {
#pragma unroll
            for (int j = 0; j < 4; ++j) {
                bf16x8 ak = *(const bf16x8*)(&KsC[(j * 16 + lr) * 128 + swz[ks]]);
                acc_s[j] = MFMA16(ak, aq[ks], acc_s[j], 0, 0, 0);
            }
        }

        const int kv0 = tile * 64;
        // ---- causal mask only on diagonal-straddling tiles (wave-uniform) ----
        if (kv0 + 63 > q0 + wave * 16) {
#pragma unroll
            for (int j = 0; j < 4; ++j)
#pragma unroll
                for (int r = 0; r < 4; ++r) {
                    const int kvg = kv0 + j * 16 + lq * 4 + r;
                    if (kvg > q_g) acc_s[j][r] = -1e30f;
                }
        }
        // ---- online softmax in log2 domain; lane owns column q ----
        float mx = -1e30f;
#pragma unroll
        for (int j = 0; j < 4; ++j)
#pragma unroll
            for (int r = 0; r < 4; ++r) mx = fmaxf(mx, acc_s[j][r]);
        mx = fmaxf(mx, __shfl_xor(mx, 16));
        mx = fmaxf(mx, __shfl_xor(mx, 32));
        const float mnew  = fmaxf(mrow, mx);
        const float alpha = exp2f(mrow - mnew);
        mrow = mnew;

        float rs = 0.0f;
#pragma unroll
        for (int j = 0; j < 4; ++j) {
            bf16 pk[4];
#pragma unroll
            for (int r = 0; r < 4; ++r) {
                float p = exp2f(acc_s[j][r] - mnew);
                rs += p;
                pk[r] = __float2bfloat16(p);
            }
            *(uint2*)(PbRow + pw[j]) = *(const uint2*)pk;   // P^T[q][kv] swizzled
        }
        rs += __shfl_xor(rs, 16);
        rs += __shfl_xor(rs, 32);
        lrow = lrow * alpha + rs;
#pragma unroll
        for (int i = 0; i < 8; ++i)
#pragma unroll
            for (int r = 0; r < 4; ++r) acc_o[i][r] *= alpha;

        // ---- O^T += V^T . P^T (Pb same-wave write->read, no barrier) ----
#pragma unroll
        for (int ks = 0; ks < 2; ++ks) {
            bf16x8 bp = *(const bf16x8*)(PbRow + swz[ks]);
#pragma unroll
            for (int i = 0; i < 8; ++i) {
                bf16x8 av = *(const bf16x8*)(&VsC[(i * 16 + lr) * 64 + swz[ks]]);
                acc_o[i] = MFMA16(av, bp, acc_o[i], 0, 0, 0);
            }
        }
    }

    // ---- epilogue: transpose O^T through LDS, coalesced 16B stores ----
    __syncthreads();
    const float inv = 1.0f / lrow;
    bf16* OtW = smem + wave * 16 * 136;       // per-wave [16][136]
#pragma unroll
    for (int i = 0; i < 8; ++i) {
        bf16 pk[4];
#pragma unroll
        for (int r = 0; r < 4; ++r) pk[r] = __float2bfloat16(acc_o[i][r] * inv);
        *(uint2*)(OtW + lr * 136 + i * 16 + lq * 4) = *(const uint2*)pk;
    }
    __builtin_amdgcn_s_waitcnt(0);            // lgkm drain within wave
    const int b_ = bh >> 4, h_ = bh & 15;
    const int ro = lane >> 2;
    const int dc = (lane & 3) * 32;
    const bf16* src = OtW + ro * 136 + dc;
    bf16* dst = O + (size_t)(b_ * 2048 + q0 + wave * 16 + ro) * 2048 + h_ * 128 + dc;
#pragma unroll
    for (int u = 0; u < 4; ++u)
        *(uint4*)(dst + u * 8) = *(const uint4*)(src + u * 8);
}

extern "C" void kernel_launch(void* const* d_in, const int* in_sizes, int n_in,
                              void* d_out, int out_size, void* d_ws, size_t ws_size,
                              hipStream_t stream)
{
    const float* x  = (const float*)d_in[0];
    const float* Wq = (const float*)d_in[1];
    const float* Wk = (const float*)d_in[2];
    const float* Wv = (const float*)d_in[3];
    const float* Wo = (const float*)d_in[4];
    float* out = (float*)d_out;

    const size_t NX = 8388608;            // B*S*E
    const size_t NW = 4194304;            // E*E
    bf16* Xb = (bf16*)d_ws;               // [B*S, E]; reused as AO after QKV
    bf16* W1 = Xb + NX;                   // Wq, later Wo
    bf16* W2 = W1 + NW;                   // Wk
    bf16* W3 = W2 + NW;                   // Wv
    bf16* Qb = W3 + NW;                   // [B,H,S,D]
    bf16* Kb = Qb + NX;                   // [B,H,S,D]
    bf16* Vb = Kb + NX;                   // [B,H,D,S]
    bf16* AO = Xb;

    cvt4<<<dim3(10240), dim3(256), 0, stream>>>(x, Wq, Wk, Wv, Xb, W1, W2, W3);
    gemm_qkv<<<dim3(32, 48), dim3(256), 0, stream>>>(Xb, W1, W2, W3, Qb, Kb, Vb);
    cvt1<<<dim3(2048), dim3(256), 0, stream>>>(Wo, W1);
    attn_fwd<<<dim3(512), dim3(512), 0, stream>>>(Qb, Kb, Vb, AO);
    gemm_o<<<dim3(32, 16), dim3(256), 0, stream>>>(AO, W1, out, 2048);
}